// Round 4
// baseline (791.248 us; speedup 1.0000x reference)
//
#include <hip/hip_runtime.h>
#include <hip/hip_bf16.h>

// Problem constants
#define HH 56
#define WWD 56
#define WIN 7
#define SHIFT 3
#define HEADS 8
#define NTOK 49        // WIN*WIN
#define NW 64          // (56/7)^2
#define CDIM 256
#define DH 32          // CDIM/HEADS
#define MROWS 100352   // B*nW*NTOK = 2048*49
#define SCALE_Q 0.17677669529663687f

typedef float floatx4 __attribute__((ext_vector_type(4)));
typedef __bf16 bf16x8 __attribute__((ext_vector_type(8)));

__device__ __forceinline__ float wave_sum(float v) {
#pragma unroll
    for (int m = 1; m < 64; m <<= 1) v += __shfl_xor(v, m);
    return v;
}

__device__ __forceinline__ void glds16(const void* g, void* l) {
    __builtin_amdgcn_global_load_lds(
        (const __attribute__((address_space(1))) void*)g,
        (__attribute__((address_space(3))) void*)l, 16, 0, 0);
}

// ---------------------------------------------------------------------------
// Weight fp32 -> bf16 conversion
__global__ __launch_bounds__(256) void convert_weights_kernel(
    const float* __restrict__ qkv_w, const float* __restrict__ proj_w,
    const float* __restrict__ fc1_w, const float* __restrict__ fc2_w,
    __hip_bfloat16* __restrict__ dst)
{
    int i = blockIdx.x * 256 + threadIdx.x;
    float v;
    if (i < 196608)       v = qkv_w[i];
    else if (i < 262144)  v = proj_w[i - 196608];
    else if (i < 524288)  v = fc1_w[i - 262144];
    else                  v = fc2_w[i - 524288];
    dst[i] = __float2bfloat16(v);
}

// ---------------------------------------------------------------------------
// LayerNorm; SHIFTED=true also applies roll(-3,-3) + window partition scatter.
template <bool SHIFTED>
__global__ __launch_bounds__(256) void ln_kernel(
    const float* __restrict__ x, const float* __restrict__ g,
    const float* __restrict__ bb, __hip_bfloat16* __restrict__ out)
{
    const int tok  = blockIdx.x * 4 + (threadIdx.x >> 6);
    const int lane = threadIdx.x & 63;
    const int c    = lane * 4;

    float4 v = *reinterpret_cast<const float4*>(x + (size_t)tok * CDIM + c);
    float s = v.x + v.y + v.z + v.w;
    s = wave_sum(s);
    const float mean = s * (1.0f / 256.0f);
    float d0 = v.x - mean, d1 = v.y - mean, d2 = v.z - mean, d3 = v.w - mean;
    float sq = d0 * d0 + d1 * d1 + d2 * d2 + d3 * d3;
    sq = wave_sum(sq);
    const float rstd = rsqrtf(sq * (1.0f / 256.0f) + 1e-5f);

    float4 gv = *reinterpret_cast<const float4*>(g + c);
    float4 bv = *reinterpret_cast<const float4*>(bb + c);

    union { __hip_bfloat16 h[4]; uint2 u; } pk;
    pk.h[0] = __float2bfloat16(d0 * rstd * gv.x + bv.x);
    pk.h[1] = __float2bfloat16(d1 * rstd * gv.y + bv.y);
    pk.h[2] = __float2bfloat16(d2 * rstd * gv.z + bv.z);
    pk.h[3] = __float2bfloat16(d3 * rstd * gv.w + bv.w);

    size_t oidx;
    if (SHIFTED) {
        int b = tok / 3136;
        int l = tok - b * 3136;
        int h = l / WWD, w = l - (l / WWD) * WWD;
        int hp = h - SHIFT; if (hp < 0) hp += HH;
        int wp = w - SHIFT; if (wp < 0) wp += WWD;
        int bwin = b * NW + (hp / WIN) * 8 + (wp / WIN);
        int n = (hp % WIN) * WIN + (wp % WIN);
        oidx = ((size_t)bwin * NTOK + n) * CDIM + c;
    } else {
        oidx = (size_t)tok * CDIM + c;
    }
    *reinterpret_cast<uint2*>(out + oidx) = pk.u;
}

// ---------------------------------------------------------------------------
// A-stationary GEMM for K=256: stage the block's full A-panel (128x256 bf16,
// 64 KB, XOR-swizzled) into LDS ONCE, then loop NTILES N-tiles of 128 cols
// with only 8KB W-tiles streaming (double-buffered; W is L2-resident so its
// ~200cy latency hides under one k-step of compute). HBM latency paid once
// per block; A never re-read across N-tiles. 1 barrier per k-step.
// MODE 0: qkv (scale q cols, bf16 out). MODE 1: proj (window-reverse scatter
// + residual add, f32 out). MODE 2: fc1 (GELU tanh-approx, bf16 out).
template <int MODE, int NTILES>
__global__ __launch_bounds__(256) void gemm_astat(
    const __hip_bfloat16* __restrict__ A,    // M x 256
    const __hip_bfloat16* __restrict__ Wt,   // (NTILES*128) x 256, K-major rows
    const float* __restrict__ bias,
    void* __restrict__ outv,
    const float* __restrict__ aux,
    int M, int Nn)
{
    __shared__ __hip_bfloat16 Asd[128 * 256];      // 64 KB, swizzled chunks
    __shared__ __hip_bfloat16 Wb[2][128 * 32];     // 2 x 8 KB

    const int tid = threadIdx.x;
    const int wave = tid >> 6, lane = tid & 63;
    const int m0 = blockIdx.x * 128;

    const int fm = lane & 15;
    const int g4 = lane >> 4;
    const int wr = (wave >> 1) * 64;
    const int wc = (wave & 1) * 64;

    // W staging lane constants (identical scheme to the proven 128x32 tile)
    const int c0 = wave * 64 + lane;
    const int c1 = 256 + c0;
    const int r0 = c0 >> 2, p0 = c0 & 3, g0 = p0 ^ ((r0 >> 1) & 3);
    const int r1 = c1 >> 2, p1 = c1 & 3, g1 = p1 ^ ((r1 >> 1) & 3);
    const int wbase0 = wave * 512;           // elements
    const int wbase1 = 2048 + wave * 512;

    // ---- stage A panel: 16 glds16/thread. dest chunk idx = i*256+tid;
    // row = idx>>5, dest chunk-in-row b = idx&31; source chunk = b ^ (row&7).
#pragma unroll
    for (int i = 0; i < 16; ++i) {
        const int idx = i * 256 + tid;
        const int row = idx >> 5, b = idx & 31;
        const int sc = b ^ (row & 7);
        glds16(A + (size_t)(m0 + row) * 256 + sc * 8,
               Asd + (i * 256 + wave * 64) * 8);
    }
    // ---- stage W tile 0
    glds16(Wt + (size_t)r0 * 256 + g0 * 8, Wb[0] + wbase0);
    glds16(Wt + (size_t)r1 * 256 + g1 * 8, Wb[0] + wbase1);

    floatx4 acc[4][4] = {};
    const int NT8 = NTILES * 8;

    for (int t = 0; t < NT8; ++t) {
        asm volatile("s_waitcnt vmcnt(0)" ::: "memory");
        __builtin_amdgcn_s_barrier();
        __builtin_amdgcn_sched_barrier(0);

        const int p = t & 1;
        if (t + 1 < NT8) {
            const int t1 = t + 1;
            const int n0t = (t1 >> 3) * 128;
            const int kc = (t1 & 7) * 32;
            glds16(Wt + (size_t)(n0t + r0) * 256 + kc + g0 * 8, Wb[1 - p] + wbase0);
            glds16(Wt + (size_t)(n0t + r1) * 256 + kc + g1 * 8, Wb[1 - p] + wbase1);
        }

        const int ks = t & 7;
        bf16x8 af[4], bfr[4];
#pragma unroll
        for (int mt = 0; mt < 4; ++mt) {
            const int row = wr + mt * 16 + fm;
            af[mt] = *reinterpret_cast<const bf16x8*>(
                Asd + row * 256 + (((ks * 4 + g4) ^ (row & 7)) * 8));
            const int nl = wc + mt * 16 + fm;
            bfr[mt] = *reinterpret_cast<const bf16x8*>(
                Wb[p] + nl * 32 + ((g4 ^ ((nl >> 1) & 3)) * 8));
        }
#pragma unroll
        for (int mt = 0; mt < 4; ++mt)
#pragma unroll
            for (int nn = 0; nn < 4; ++nn)
                acc[mt][nn] = __builtin_amdgcn_mfma_f32_16x16x32_bf16(
                    af[mt], bfr[nn], acc[mt][nn], 0, 0, 0);

        if (ks == 7) {
            // ---- epilogue for N-tile ti
            const int ti = t >> 3;
            const int nbase = ti * 128;
            float bv[4];
#pragma unroll
            for (int nn = 0; nn < 4; ++nn)
                bv[nn] = bias[nbase + wc + nn * 16 + fm];
#pragma unroll
            for (int mt = 0; mt < 4; ++mt) {
#pragma unroll
                for (int rr = 0; rr < 4; ++rr) {
                    const int m_g = m0 + wr + mt * 16 + g4 * 4 + rr;
                    size_t row_idx = 0;
                    if (MODE == 1) {
                        int bwin = m_g / NTOK;
                        int ntok = m_g - bwin * NTOK;
                        int b = bwin >> 6, wi = bwin & 63;
                        int r2 = ntok / WIN, cc = ntok - r2 * WIN;
                        int hp = (wi >> 3) * WIN + r2;
                        int wp = (wi & 7) * WIN + cc;
                        int h = hp + SHIFT; if (h >= HH) h -= HH;
                        int w = wp + SHIFT; if (w >= WWD) w -= WWD;
                        row_idx = ((size_t)b * 3136 + h * WWD + w) * CDIM;
                    }
#pragma unroll
                    for (int nn = 0; nn < 4; ++nn) {
                        const int n_g = nbase + wc + nn * 16 + fm;
                        float val = acc[mt][nn][rr] + bv[nn];
                        if (MODE == 0) {
                            if (n_g < 256) val *= SCALE_Q;
                            reinterpret_cast<__hip_bfloat16*>(outv)[(size_t)m_g * Nn + n_g] =
                                __float2bfloat16(val);
                        } else if (MODE == 2) {
                            // GELU tanh-approx (robust 1 - 2/(e+1) form)
                            float u  = val;
                            float y2 = 1.5957691216057308f * u
                                     * (1.0f + 0.044715f * u * u);
                            float e  = __expf(y2);
                            float th = 1.0f - 2.0f / (e + 1.0f);
                            float gl = 0.5f * u * (1.0f + th);
                            reinterpret_cast<__hip_bfloat16*>(outv)[(size_t)m_g * Nn + n_g] =
                                __float2bfloat16(gl);
                        } else {   // MODE 1
                            size_t idx = row_idx + n_g;
                            reinterpret_cast<float*>(outv)[idx] = aux[idx] + val;
                        }
                        acc[mt][nn][rr] = 0.0f;
                    }
                }
            }
        }
    }
}

// ---------------------------------------------------------------------------
// fc2 GEMM: K=1024, tile 128x256 (full N in one block -> A read exactly once),
// BK=32, 3-buffer depth-2 pipeline (proven R2 structure), counted vmcnt(6).
// out = aux + A@W2^T + b, f32.
__global__ __launch_bounds__(256, 2) void gemm_k1024(
    const __hip_bfloat16* __restrict__ A,    // M x 1024
    const __hip_bfloat16* __restrict__ Wt,   // 256 x 1024
    const float* __restrict__ bias,
    float* __restrict__ outv,
    const float* __restrict__ aux)
{
    __shared__ __hip_bfloat16 As[3][128 * 32];   // 3 x 8 KB
    __shared__ __hip_bfloat16 Bs[3][256 * 32];   // 3 x 16 KB

    const int tid = threadIdx.x;
    const int wave = tid >> 6, lane = tid & 63;
    const int m0 = blockIdx.x * 128;

    const int fm = lane & 15;
    const int g4 = lane >> 4;
    const int wr = (wave >> 1) * 64;
    const int wc = (wave & 1) * 128;

    floatx4 acc[4][8] = {};

    // staging lane constants: A uses c0,c1 (128 rows); B uses c0..c3 (256 rows)
    const int c0 = wave * 64 + lane;
    int rj[4], gj[4];
#pragma unroll
    for (int j = 0; j < 4; ++j) {
        const int cj = j * 256 + c0;
        rj[j] = cj >> 2;
        const int pj = cj & 3;
        gj[j] = pj ^ ((rj[j] >> 1) & 3);
    }
    const __hip_bfloat16* gA0 = A + (size_t)(m0 + rj[0]) * 1024 + gj[0] * 8;
    const __hip_bfloat16* gA1 = A + (size_t)(m0 + rj[1]) * 1024 + gj[1] * 8;
    const __hip_bfloat16* gB0 = Wt + (size_t)rj[0] * 1024 + gj[0] * 8;
    const __hip_bfloat16* gB1 = Wt + (size_t)rj[1] * 1024 + gj[1] * 8;
    const __hip_bfloat16* gB2 = Wt + (size_t)rj[2] * 1024 + gj[2] * 8;
    const __hip_bfloat16* gB3 = Wt + (size_t)rj[3] * 1024 + gj[3] * 8;
    const int ab0 = wave * 512, ab1 = 2048 + wave * 512;
    const int bb0 = wave * 512, bb1 = 2048 + wave * 512;
    const int bb2 = 4096 + wave * 512, bb3 = 6144 + wave * 512;

    const int nt = 32;   // 1024/32

    // ---- prologue: stage tiles 0,1
#pragma unroll
    for (int pp = 0; pp < 2; ++pp) {
        const int kp = pp << 5;
        glds16(gA0 + kp, As[pp] + ab0);
        glds16(gA1 + kp, As[pp] + ab1);
        glds16(gB0 + kp, Bs[pp] + bb0);
        glds16(gB1 + kp, Bs[pp] + bb1);
        glds16(gB2 + kp, Bs[pp] + bb2);
        glds16(gB3 + kp, Bs[pp] + bb3);
    }
    asm volatile("s_waitcnt vmcnt(6)" ::: "memory");
    __builtin_amdgcn_s_barrier();
    __builtin_amdgcn_sched_barrier(0);

    int cur = 0;
    for (int tt = 0; tt < nt; ++tt) {
        if (tt + 2 < nt) {
            const int nx2 = (cur >= 1) ? cur - 1 : cur + 2;
            const int k2 = (tt + 2) << 5;
            glds16(gA0 + k2, As[nx2] + ab0);
            glds16(gA1 + k2, As[nx2] + ab1);
            glds16(gB0 + k2, Bs[nx2] + bb0);
            glds16(gB1 + k2, Bs[nx2] + bb1);
            glds16(gB2 + k2, Bs[nx2] + bb2);
            glds16(gB3 + k2, Bs[nx2] + bb3);
        }

        const __hip_bfloat16* Ac = As[cur];
        const __hip_bfloat16* Bc = Bs[cur];
        bf16x8 af[4], bfr[8];
#pragma unroll
        for (int mt = 0; mt < 4; ++mt) {
            const int ml = wr + mt * 16 + fm;
            af[mt] = *reinterpret_cast<const bf16x8*>(
                Ac + ml * 32 + ((g4 ^ ((ml >> 1) & 3)) * 8));
        }
#pragma unroll
        for (int nn = 0; nn < 8; ++nn) {
            const int nl = wc + nn * 16 + fm;
            bfr[nn] = *reinterpret_cast<const bf16x8*>(
                Bc + nl * 32 + ((g4 ^ ((nl >> 1) & 3)) * 8));
        }
#pragma unroll
        for (int mt = 0; mt < 4; ++mt)
#pragma unroll
            for (int nn = 0; nn < 8; ++nn)
                acc[mt][nn] = __builtin_amdgcn_mfma_f32_16x16x32_bf16(
                    af[mt], bfr[nn], acc[mt][nn], 0, 0, 0);

        if (tt + 1 < nt) {
            if (tt + 2 < nt)
                asm volatile("s_waitcnt vmcnt(6) lgkmcnt(0)" ::: "memory");
            else
                asm volatile("s_waitcnt vmcnt(0) lgkmcnt(0)" ::: "memory");
            __builtin_amdgcn_s_barrier();
            __builtin_amdgcn_sched_barrier(0);
        }
        cur = (cur >= 2) ? 0 : cur + 1;
    }

    float bv[8];
#pragma unroll
    for (int nn = 0; nn < 8; ++nn) bv[nn] = bias[wc + nn * 16 + fm];

#pragma unroll
    for (int mt = 0; mt < 4; ++mt) {
#pragma unroll
        for (int rr = 0; rr < 4; ++rr) {
            const int m_g = m0 + wr + mt * 16 + g4 * 4 + rr;
#pragma unroll
            for (int nn = 0; nn < 8; ++nn) {
                const int n_g = wc + nn * 16 + fm;
                const size_t idx = (size_t)m_g * CDIM + n_g;
                outv[idx] = aux[idx] + acc[mt][nn][rr] + bv[nn];
            }
        }
    }
}

// ---------------------------------------------------------------------------
// Attention v5 (MFMA + cheap 3-softmax): one wave per (window, head).
__global__ __launch_bounds__(256) void attn_kernel(
    const __hip_bfloat16* __restrict__ qkv,   // (B_,49,768) bf16, q pre-scaled
    const float* __restrict__ rpb_table,      // (169,8)
    const float* __restrict__ sal_fg,         // (B_,49,49): row 0 = key mask
    __hip_bfloat16* __restrict__ o)           // (B_,49,256)
{
    __shared__ unsigned short Pl[4][64 * 40];   // [query][keyHalf] bf16
    __shared__ unsigned short Vt[4][32 * 72];   // [d][key] bf16, stride 72
    __shared__ float rpb_l[4][176];

    const int t = threadIdx.x;
    const int wave = t >> 6, lane = t & 63;
    const int lane15 = lane & 15, g4 = lane >> 4;
    const int b_ = blockIdx.x >> 1;
    const int h = ((blockIdx.x & 1) << 2) | wave;

    unsigned short* Pw = Pl[wave];
    unsigned short* Vw = Vt[wave];
    float* rpbw = rpb_l[wave];

    const unsigned short* qkv_u = reinterpret_cast<const unsigned short*>(qkv);
    const size_t base = (size_t)b_ * (NTOK * 768) + h * DH;

#pragma unroll
    for (int it = 0; it < 32; ++it) {
        int idx = it * 64 + lane;
        int key = idx >> 5, d = idx & 31;
        unsigned short v = (key < NTOK) ? qkv_u[base + key * 768 + 512 + d]
                                        : (unsigned short)0;
        Vw[d * 72 + key] = v;
    }
#pragma unroll
    for (int it = 0; it < 3; ++it) {
        int i = it * 64 + lane;
        if (i < 169) rpbw[i] = rpb_table[i * 8 + h];
    }
    float sfv = (lane < NTOK) ? sal_fg[(size_t)b_ * (NTOK * NTOK) + lane] : -100.f;
    const unsigned long long fgmask = __ballot(sfv == 0.0f);

    bf16x8 kf[4], qf[4];
#pragma unroll
    for (int mt = 0; mt < 4; ++mt)
        kf[mt] = *reinterpret_cast<const bf16x8*>(
            qkv_u + base + (size_t)(mt * 16 + lane15) * 768 + 256 + g4 * 8);
#pragma unroll
    for (int nt = 0; nt < 4; ++nt)
        qf[nt] = *reinterpret_cast<const bf16x8*>(
            qkv_u + base + (size_t)(nt * 16 + lane15) * 768 + g4 * 8);

    floatx4 S[4][4] = {};
#pragma unroll
    for (int mt = 0; mt < 4; ++mt)
#pragma unroll
        for (int nt = 0; nt < 4; ++nt)
            S[mt][nt] = __builtin_amdgcn_mfma_f32_16x16x32_bf16(
                kf[mt], qf[nt], S[mt][nt], 0, 0, 0);

    const int wr_ = (b_ & 63) >> 3, wc_ = (b_ & 63) & 7;
    int qlin[4], qreg[4];
#pragma unroll
    for (int nt = 0; nt < 4; ++nt) {
        int q = nt * 16 + lane15;
        int qr = (q * 147) >> 10, qc = q - qr * 7;
        qlin[nt] = q + 6 * qr + 84;
        qreg[nt] = ((wr_ == 7) ? ((qr < 4) ? 1 : 2) : 0) * 3
                 + ((wc_ == 7) ? ((qc < 4) ? 1 : 2) : 0);
    }

#pragma unroll
    for (int mt = 0; mt < 4; ++mt)
#pragma unroll
        for (int r = 0; r < 4; ++r) {
            int key = mt * 16 + g4 * 4 + r;
            int kr = (key * 147) >> 10, kc = key - kr * 7;
            int klin = key + 6 * kr;
            int kreg = ((wr_ == 7) ? ((kr < 4) ? 1 : 2) : 0) * 3
                     + ((wc_ == 7) ? ((kc < 4) ? 1 : 2) : 0);
            bool pad = key >= NTOK;
#pragma unroll
            for (int nt = 0; nt < 4; ++nt) {
                int idx = qlin[nt] - klin;
                idx = idx < 0 ? 0 : (idx > 168 ? 168 : idx);
                float s = S[mt][nt][r] + rpbw[idx]
                        + ((qreg[nt] == kreg) ? 0.f : -100.f);
                S[mt][nt][r] = pad ? -1e30f : s;
            }
        }

    float Cfg[4], Cbg[4];
#pragma unroll
    for (int nt = 0; nt < 4; ++nt) {
        float mfg = -3e38f, mbg = -3e38f;
#pragma unroll
        for (int mt = 0; mt < 4; ++mt)
#pragma unroll
            for (int r = 0; r < 4; ++r) {
                int key = mt * 16 + g4 * 4 + r;
                bool fg = (fgmask >> key) & 1ULL;
                float s = S[mt][nt][r];
                mfg = fg ? fmaxf(mfg, s) : mfg;
                mbg = fg ? mbg : fmaxf(mbg, s);
            }
        mfg = fmaxf(mfg, __shfl_xor(mfg, 16)); mfg = fmaxf(mfg, __shfl_xor(mfg, 32));
        mbg = fmaxf(mbg, __shfl_xor(mbg, 16)); mbg = fmaxf(mbg, __shfl_xor(mbg, 32));
        float t1 = 0.f, t2 = 0.f;
#pragma unroll
        for (int mt = 0; mt < 4; ++mt)
#pragma unroll
            for (int r = 0; r < 4; ++r) {
                int key = mt * 16 + g4 * 4 + r;
                bool fg = (fgmask >> key) & 1ULL;
                float e = __expf(S[mt][nt][r] - (fg ? mfg : mbg));
                S[mt][nt][r] = e;
                t1 += fg ? e : 0.f;
                t2 += fg ? 0.f : e;
            }
        t1 += __shfl_xor(t1, 16); t1 += __shfl_xor(t1, 32);
        t2 += __shfl_xor(t2, 16); t2 += __shfl_xor(t2, 32);
        const float m0 = fmaxf(mfg, mbg);
        const float m1 = fmaxf(mfg, mbg - 100.f);
        const float m2 = fmaxf(mfg - 100.f, mbg);
        const float a1 = __expf(mfg - m0),          a2 = __expf(mbg - m0);
        const float b1 = __expf(mfg - m1),          b2 = __expf(mbg - 100.f - m1);
        const float c1 = __expf(mfg - 100.f - m2),  c2 = __expf(mbg - m2);
        const float r0 = 1.f / (t1 * a1 + t2 * a2);
        const float r1 = 1.f / (t1 * b1 + t2 * b2);
        const float r2 = 1.f / (t1 * c1 + t2 * c2);
        Cfg[nt] = a1 * r0 + b1 * r1 - c1 * r2;
        Cbg[nt] = a2 * r0 + b2 * r1 - c2 * r2;
    }

    floatx4 Oc[4][2] = {};
#pragma unroll
    for (int kc = 0; kc < 2; ++kc) {
#pragma unroll
        for (int mh = 0; mh < 2; ++mh) {
            const int mt = kc * 2 + mh;
#pragma unroll
            for (int rp = 0; rp < 2; ++rp) {
                const int key0 = mt * 16 + g4 * 4 + 2 * rp;
                const bool fg0 = (fgmask >> key0) & 1ULL;
                const bool fg1 = (fgmask >> (key0 + 1)) & 1ULL;
                const int keyLocal = key0 - kc * 32;
#pragma unroll
                for (int nt = 0; nt < 4; ++nt) {
                    float pA = S[mt][nt][2 * rp]     * (fg0 ? Cfg[nt] : Cbg[nt]);
                    float pB = S[mt][nt][2 * rp + 1] * (fg1 ? Cfg[nt] : Cbg[nt]);
                    union { __hip_bfloat16 hh[2]; unsigned u; } pk;
                    pk.hh[0] = __float2bfloat16(pA);
                    pk.hh[1] = __float2bfloat16(pB);
                    const int q = nt * 16 + lane15;
                    *reinterpret_cast<unsigned*>(Pw + q * 40 + keyLocal) = pk.u;
                }
            }
        }
        bf16x8 pa[4], vb[2];
#pragma unroll
        for (int mtile = 0; mtile < 4; ++mtile)
            pa[mtile] = *reinterpret_cast<const bf16x8*>(
                Pw + (mtile * 16 + lane15) * 40 + g4 * 8);
#pragma unroll
        for (int n2 = 0; n2 < 2; ++n2)
            vb[n2] = *reinterpret_cast<const bf16x8*>(
                Vw + (n2 * 16 + lane15) * 72 + kc * 32 + g4 * 8);
#pragma unroll
        for (int mtile = 0; mtile < 4; ++mtile)
#pragma unroll
            for (int n2 = 0; n2 < 2; ++n2)
                Oc[mtile][n2] = __builtin_amdgcn_mfma_f32_16x16x32_bf16(
                    pa[mtile], vb[n2], Oc[mtile][n2], 0, 0, 0);
    }

#pragma unroll
    for (int mt = 0; mt < 4; ++mt)
#pragma unroll
        for (int r = 0; r < 4; ++r) {
            int query = mt * 16 + g4 * 4 + r;
            if (query < NTOK) {
                __hip_bfloat16* op = o + ((size_t)b_ * NTOK + query) * CDIM + h * DH;
#pragma unroll
                for (int n2 = 0; n2 < 2; ++n2)
                    op[n2 * 16 + lane15] = __float2bfloat16(Oc[mt][n2][r]);
            }
        }
}

// ---------------------------------------------------------------------------
extern "C" void kernel_launch(void* const* d_in, const int* in_sizes, int n_in,
                              void* d_out, int out_size, void* d_ws, size_t ws_size,
                              hipStream_t stream)
{
    const float* x        = (const float*)d_in[0];
    const float* qkv_w    = (const float*)d_in[1];
    const float* qkv_b    = (const float*)d_in[2];
    const float* rpb_tab  = (const float*)d_in[3];
    const float* proj_w   = (const float*)d_in[4];
    const float* proj_b   = (const float*)d_in[5];
    const float* n1g      = (const float*)d_in[6];
    const float* n1b      = (const float*)d_in[7];
    const float* n2g      = (const float*)d_in[8];
    const float* n2b      = (const float*)d_in[9];
    const float* fc1_w    = (const float*)d_in[10];
    const float* fc1_b    = (const float*)d_in[11];
    const float* fc2_w    = (const float*)d_in[12];
    const float* fc2_b    = (const float*)d_in[13];
    const float* sal_fg   = (const float*)d_in[15];

    char* ws = (char*)d_ws;
    __hip_bfloat16* regA = (__hip_bfloat16*)ws;
    __hip_bfloat16* regB = (__hip_bfloat16*)(ws + 205520896);
    float*          x2   = (float*)(ws + 205520896 + 51380224);
    __hip_bfloat16* wbf  = (__hip_bfloat16*)(ws + 205520896 + 51380224 + 102760448);
    __hip_bfloat16* wqkv  = wbf;
    __hip_bfloat16* wproj = wbf + 196608;
    __hip_bfloat16* wfc1  = wbf + 262144;
    __hip_bfloat16* wfc2  = wbf + 524288;

    convert_weights_kernel<<<3072, 256, 0, stream>>>(qkv_w, proj_w, fc1_w, fc2_w, wbf);

    ln_kernel<true><<<MROWS / 4, 256, 0, stream>>>(x, n1g, n1b, regB);

    gemm_astat<0, 6><<<MROWS / 128, 256, 0, stream>>>(
        regB, wqkv, qkv_b, regA, nullptr, MROWS, 768);

    attn_kernel<<<2048 * 2, 256, 0, stream>>>(regA, rpb_tab, sal_fg, regB);

    gemm_astat<1, 2><<<MROWS / 128, 256, 0, stream>>>(
        regB, wproj, proj_b, x2, x, MROWS, 256);

    ln_kernel<false><<<MROWS / 4, 256, 0, stream>>>(x2, n2g, n2b, regB);

    gemm_astat<2, 8><<<MROWS / 128, 256, 0, stream>>>(
        regB, wfc1, fc1_b, regA, nullptr, MROWS, 1024);

    gemm_k1024<<<MROWS / 128, 256, 0, stream>>>(regA, wfc2, fc2_b, (float*)d_out, x2);
}

// Round 5
// 684.883 us; speedup vs baseline: 1.1553x; 1.1553x over previous
//
#include <hip/hip_runtime.h>
#include <hip/hip_bf16.h>

// Problem constants
#define HH 56
#define WWD 56
#define WIN 7
#define SHIFT 3
#define HEADS 8
#define NTOK 49        // WIN*WIN
#define NW 64          // (56/7)^2
#define CDIM 256
#define DH 32          // CDIM/HEADS
#define MROWS 100352   // B*nW*NTOK = 2048*49
#define SCALE_Q 0.17677669529663687f

typedef float floatx4 __attribute__((ext_vector_type(4)));
typedef __bf16 bf16x8 __attribute__((ext_vector_type(8)));

__device__ __forceinline__ float wave_sum(float v) {
#pragma unroll
    for (int m = 1; m < 64; m <<= 1) v += __shfl_xor(v, m);
    return v;
}

__device__ __forceinline__ void glds16(const void* g, void* l) {
    __builtin_amdgcn_global_load_lds(
        (const __attribute__((address_space(1))) void*)g,
        (__attribute__((address_space(3))) void*)l, 16, 0, 0);
}

// ---------------------------------------------------------------------------
// Weight fp32 -> bf16 conversion
__global__ __launch_bounds__(256) void convert_weights_kernel(
    const float* __restrict__ qkv_w, const float* __restrict__ proj_w,
    const float* __restrict__ fc1_w, const float* __restrict__ fc2_w,
    __hip_bfloat16* __restrict__ dst)
{
    int i = blockIdx.x * 256 + threadIdx.x;
    float v;
    if (i < 196608)       v = qkv_w[i];
    else if (i < 262144)  v = proj_w[i - 196608];
    else if (i < 524288)  v = fc1_w[i - 262144];
    else                  v = fc2_w[i - 524288];
    dst[i] = __float2bfloat16(v);
}

// ---------------------------------------------------------------------------
// LayerNorm; SHIFTED=true also applies roll(-3,-3) + window partition scatter.
template <bool SHIFTED>
__global__ __launch_bounds__(256) void ln_kernel(
    const float* __restrict__ x, const float* __restrict__ g,
    const float* __restrict__ bb, __hip_bfloat16* __restrict__ out)
{
    const int tok  = blockIdx.x * 4 + (threadIdx.x >> 6);
    const int lane = threadIdx.x & 63;
    const int c    = lane * 4;

    float4 v = *reinterpret_cast<const float4*>(x + (size_t)tok * CDIM + c);
    float s = v.x + v.y + v.z + v.w;
    s = wave_sum(s);
    const float mean = s * (1.0f / 256.0f);
    float d0 = v.x - mean, d1 = v.y - mean, d2 = v.z - mean, d3 = v.w - mean;
    float sq = d0 * d0 + d1 * d1 + d2 * d2 + d3 * d3;
    sq = wave_sum(sq);
    const float rstd = rsqrtf(sq * (1.0f / 256.0f) + 1e-5f);

    float4 gv = *reinterpret_cast<const float4*>(g + c);
    float4 bv = *reinterpret_cast<const float4*>(bb + c);

    union { __hip_bfloat16 h[4]; uint2 u; } pk;
    pk.h[0] = __float2bfloat16(d0 * rstd * gv.x + bv.x);
    pk.h[1] = __float2bfloat16(d1 * rstd * gv.y + bv.y);
    pk.h[2] = __float2bfloat16(d2 * rstd * gv.z + bv.z);
    pk.h[3] = __float2bfloat16(d3 * rstd * gv.w + bv.w);

    size_t oidx;
    if (SHIFTED) {
        int b = tok / 3136;
        int l = tok - b * 3136;
        int h = l / WWD, w = l - (l / WWD) * WWD;
        int hp = h - SHIFT; if (hp < 0) hp += HH;
        int wp = w - SHIFT; if (wp < 0) wp += WWD;
        int bwin = b * NW + (hp / WIN) * 8 + (wp / WIN);
        int n = (hp % WIN) * WIN + (wp % WIN);
        oidx = ((size_t)bwin * NTOK + n) * CDIM + c;
    } else {
        oidx = (size_t)tok * CDIM + c;
    }
    *reinterpret_cast<uint2*>(out + oidx) = pk.u;
}

// ---------------------------------------------------------------------------
// Wide bf16 MFMA GEMM: 128x256 tile, BK=32, global_load_lds(16B), XOR-swizzled
// LDS chunks, 3-buffer depth-2 pipeline with counted s_waitcnt vmcnt(6) + raw
// s_barrier (R2-proven schedule, fattened: 32 MFMA/wave/step vs 16 -> half the
// k-steps against the ~fixed per-step latency cost). Bijective XCD-chunked
// blockIdx swizzle. 72 KB LDS -> 2 blocks/CU.
// MODE 0: qkv (scale q cols, bf16 out). MODE 1: proj (window-reverse scatter +
// residual, f32). MODE 2: fc1 (GELU tanh-approx, bf16). MODE 3: fc2 (residual,
// f32).
template <int MODE>
__device__ __forceinline__ void gemm_wide_body(
    const __hip_bfloat16* __restrict__ A,
    const __hip_bfloat16* __restrict__ Wt,
    const float* __restrict__ bias,
    void* __restrict__ outv,
    const float* __restrict__ aux,
    int M, int Nn, int K)
{
    __shared__ __hip_bfloat16 As[3][128 * 32];   // 3 x 8 KB
    __shared__ __hip_bfloat16 Bs[3][256 * 32];   // 3 x 16 KB

    const int tid = threadIdx.x;
    const int wave = tid >> 6, lane = tid & 63;

    // ---- XCD-aware chunked remap (bijective, m204 form)
    const int nwg  = gridDim.x * gridDim.y;
    const int orig = blockIdx.y * gridDim.x + blockIdx.x;
    const int q = nwg >> 3, r = nwg & 7;
    const int xcd = orig & 7, loc = orig >> 3;
    const int lin = (xcd < r ? xcd * (q + 1) : r * (q + 1) + (xcd - r) * q) + loc;
    const int bx = lin % gridDim.x;
    const int by = lin / gridDim.x;

    const int m0 = by * 128, n0 = bx * 256;
    const int fm = lane & 15;
    const int g4 = lane >> 4;
    const int wr = (wave >> 1) * 64;     // 2 row-groups of 64
    const int wc = (wave & 1) * 128;     // 2 col-groups of 128

    floatx4 acc[4][8] = {};

    // staging lane constants: A uses chunks j=0,1 (128 rows); B uses j=0..3
    const int c0 = wave * 64 + lane;
    int rj[4], gj[4];
#pragma unroll
    for (int j = 0; j < 4; ++j) {
        const int cj = j * 256 + c0;
        rj[j] = cj >> 2;
        const int pj = cj & 3;
        gj[j] = pj ^ ((rj[j] >> 1) & 3);
    }
    const __hip_bfloat16* gA0 = A + (size_t)(m0 + rj[0]) * K + gj[0] * 8;
    const __hip_bfloat16* gA1 = A + (size_t)(m0 + rj[1]) * K + gj[1] * 8;
    const __hip_bfloat16* gB0 = Wt + (size_t)(n0 + rj[0]) * K + gj[0] * 8;
    const __hip_bfloat16* gB1 = Wt + (size_t)(n0 + rj[1]) * K + gj[1] * 8;
    const __hip_bfloat16* gB2 = Wt + (size_t)(n0 + rj[2]) * K + gj[2] * 8;
    const __hip_bfloat16* gB3 = Wt + (size_t)(n0 + rj[3]) * K + gj[3] * 8;
    const int ab0 = wave * 512, ab1 = 2048 + wave * 512;
    const int bb0 = wave * 512, bb1 = 2048 + wave * 512;
    const int bb2 = 4096 + wave * 512, bb3 = 6144 + wave * 512;

    const int nt = K >> 5;

    // ---- prologue: stage tiles 0,1
#pragma unroll
    for (int pp = 0; pp < 2; ++pp) {
        const int kp = pp << 5;
        glds16(gA0 + kp, As[pp] + ab0);
        glds16(gA1 + kp, As[pp] + ab1);
        glds16(gB0 + kp, Bs[pp] + bb0);
        glds16(gB1 + kp, Bs[pp] + bb1);
        glds16(gB2 + kp, Bs[pp] + bb2);
        glds16(gB3 + kp, Bs[pp] + bb3);
    }
    asm volatile("s_waitcnt vmcnt(6)" ::: "memory");   // tile 0 resident
    __builtin_amdgcn_s_barrier();
    __builtin_amdgcn_sched_barrier(0);

    int cur = 0;
    for (int tt = 0; tt < nt; ++tt) {
        if (tt + 2 < nt) {
            const int nx2 = (cur >= 1) ? cur - 1 : cur + 2;
            const int k2 = (tt + 2) << 5;
            glds16(gA0 + k2, As[nx2] + ab0);
            glds16(gA1 + k2, As[nx2] + ab1);
            glds16(gB0 + k2, Bs[nx2] + bb0);
            glds16(gB1 + k2, Bs[nx2] + bb1);
            glds16(gB2 + k2, Bs[nx2] + bb2);
            glds16(gB3 + k2, Bs[nx2] + bb3);
        }

        const __hip_bfloat16* Ac = As[cur];
        const __hip_bfloat16* Bc = Bs[cur];
        bf16x8 af[4], bfr[8];
#pragma unroll
        for (int mt = 0; mt < 4; ++mt) {
            const int ml = wr + mt * 16 + fm;
            af[mt] = *reinterpret_cast<const bf16x8*>(
                Ac + ml * 32 + ((g4 ^ ((ml >> 1) & 3)) * 8));
        }
#pragma unroll
        for (int nn = 0; nn < 8; ++nn) {
            const int nl = wc + nn * 16 + fm;
            bfr[nn] = *reinterpret_cast<const bf16x8*>(
                Bc + nl * 32 + ((g4 ^ ((nl >> 1) & 3)) * 8));
        }
#pragma unroll
        for (int mt = 0; mt < 4; ++mt)
#pragma unroll
            for (int nn = 0; nn < 8; ++nn)
                acc[mt][nn] = __builtin_amdgcn_mfma_f32_16x16x32_bf16(
                    af[mt], bfr[nn], acc[mt][nn], 0, 0, 0);

        if (tt + 1 < nt) {
            // vmcnt(6): tile t+1 resident, tile t+2's 6 loads stay in flight
            // across the barrier. lgkmcnt(0): this wave's ds_reads of buf[cur]
            // done before any wave overwrites it next iter.
            if (tt + 2 < nt)
                asm volatile("s_waitcnt vmcnt(6) lgkmcnt(0)" ::: "memory");
            else
                asm volatile("s_waitcnt vmcnt(0) lgkmcnt(0)" ::: "memory");
            __builtin_amdgcn_s_barrier();
            __builtin_amdgcn_sched_barrier(0);
        }
        cur = (cur >= 2) ? 0 : cur + 1;
    }

    float bv[8];
#pragma unroll
    for (int nn = 0; nn < 8; ++nn) bv[nn] = bias[n0 + wc + nn * 16 + fm];

#pragma unroll
    for (int mt = 0; mt < 4; ++mt) {
#pragma unroll
        for (int rr = 0; rr < 4; ++rr) {
            const int m_g = m0 + wr + mt * 16 + g4 * 4 + rr;
            size_t row_idx = 0;
            if (MODE == 1) {
                int bwin = m_g / NTOK;
                int ntok = m_g - bwin * NTOK;
                int b = bwin >> 6, wi = bwin & 63;
                int r2 = ntok / WIN, cc = ntok - r2 * WIN;
                int hp = (wi >> 3) * WIN + r2;
                int wp = (wi & 7) * WIN + cc;
                int h = hp + SHIFT; if (h >= HH) h -= HH;
                int w = wp + SHIFT; if (w >= WWD) w -= WWD;
                row_idx = ((size_t)b * 3136 + h * WWD + w) * CDIM;
            }
#pragma unroll
            for (int nn = 0; nn < 8; ++nn) {
                const int n_g = n0 + wc + nn * 16 + fm;
                float val = acc[mt][nn][rr] + bv[nn];
                if (MODE == 0) {
                    if (n_g < 256) val *= SCALE_Q;
                    reinterpret_cast<__hip_bfloat16*>(outv)[(size_t)m_g * Nn + n_g] =
                        __float2bfloat16(val);
                } else if (MODE == 2) {
                    // GELU tanh-approx (robust 1 - 2/(e+1) form)
                    float u  = val;
                    float y2 = 1.5957691216057308f * u
                             * (1.0f + 0.044715f * u * u);
                    float e  = __expf(y2);
                    float th = 1.0f - 2.0f / (e + 1.0f);
                    float gl = 0.5f * u * (1.0f + th);
                    reinterpret_cast<__hip_bfloat16*>(outv)[(size_t)m_g * Nn + n_g] =
                        __float2bfloat16(gl);
                } else if (MODE == 3) {
                    size_t idx = (size_t)m_g * CDIM + n_g;
                    reinterpret_cast<float*>(outv)[idx] = aux[idx] + val;
                } else {   // MODE 1
                    size_t idx = row_idx + n_g;
                    reinterpret_cast<float*>(outv)[idx] = aux[idx] + val;
                }
            }
        }
    }
}

// Distinct symbols per stage for per-dispatch profiling visibility.
__global__ __launch_bounds__(256, 2) void gemm_qkv(
    const __hip_bfloat16* __restrict__ A, const __hip_bfloat16* __restrict__ Wt,
    const float* __restrict__ bias, void* __restrict__ outv,
    const float* __restrict__ aux, int M, int Nn, int K)
{ gemm_wide_body<0>(A, Wt, bias, outv, aux, M, Nn, K); }

__global__ __launch_bounds__(256, 2) void gemm_proj(
    const __hip_bfloat16* __restrict__ A, const __hip_bfloat16* __restrict__ Wt,
    const float* __restrict__ bias, void* __restrict__ outv,
    const float* __restrict__ aux, int M, int Nn, int K)
{ gemm_wide_body<1>(A, Wt, bias, outv, aux, M, Nn, K); }

__global__ __launch_bounds__(256, 2) void gemm_fc1(
    const __hip_bfloat16* __restrict__ A, const __hip_bfloat16* __restrict__ Wt,
    const float* __restrict__ bias, void* __restrict__ outv,
    const float* __restrict__ aux, int M, int Nn, int K)
{ gemm_wide_body<2>(A, Wt, bias, outv, aux, M, Nn, K); }

__global__ __launch_bounds__(256, 2) void gemm_fc2(
    const __hip_bfloat16* __restrict__ A, const __hip_bfloat16* __restrict__ Wt,
    const float* __restrict__ bias, void* __restrict__ outv,
    const float* __restrict__ aux, int M, int Nn, int K)
{ gemm_wide_body<3>(A, Wt, bias, outv, aux, M, Nn, K); }

// ---------------------------------------------------------------------------
// Attention v5 (MFMA + cheap 3-softmax): one wave per (window, head).
__global__ __launch_bounds__(256) void attn_kernel(
    const __hip_bfloat16* __restrict__ qkv,   // (B_,49,768) bf16, q pre-scaled
    const float* __restrict__ rpb_table,      // (169,8)
    const float* __restrict__ sal_fg,         // (B_,49,49): row 0 = key mask
    __hip_bfloat16* __restrict__ o)           // (B_,49,256)
{
    __shared__ unsigned short Pl[4][64 * 40];   // [query][keyHalf] bf16
    __shared__ unsigned short Vt[4][32 * 72];   // [d][key] bf16, stride 72
    __shared__ float rpb_l[4][176];

    const int t = threadIdx.x;
    const int wave = t >> 6, lane = t & 63;
    const int lane15 = lane & 15, g4 = lane >> 4;
    const int b_ = blockIdx.x >> 1;
    const int h = ((blockIdx.x & 1) << 2) | wave;

    unsigned short* Pw = Pl[wave];
    unsigned short* Vw = Vt[wave];
    float* rpbw = rpb_l[wave];

    const unsigned short* qkv_u = reinterpret_cast<const unsigned short*>(qkv);
    const size_t base = (size_t)b_ * (NTOK * 768) + h * DH;

#pragma unroll
    for (int it = 0; it < 32; ++it) {
        int idx = it * 64 + lane;
        int key = idx >> 5, d = idx & 31;
        unsigned short v = (key < NTOK) ? qkv_u[base + key * 768 + 512 + d]
                                        : (unsigned short)0;
        Vw[d * 72 + key] = v;
    }
#pragma unroll
    for (int it = 0; it < 3; ++it) {
        int i = it * 64 + lane;
        if (i < 169) rpbw[i] = rpb_table[i * 8 + h];
    }
    float sfv = (lane < NTOK) ? sal_fg[(size_t)b_ * (NTOK * NTOK) + lane] : -100.f;
    const unsigned long long fgmask = __ballot(sfv == 0.0f);

    bf16x8 kf[4], qf[4];
#pragma unroll
    for (int mt = 0; mt < 4; ++mt)
        kf[mt] = *reinterpret_cast<const bf16x8*>(
            qkv_u + base + (size_t)(mt * 16 + lane15) * 768 + 256 + g4 * 8);
#pragma unroll
    for (int nt = 0; nt < 4; ++nt)
        qf[nt] = *reinterpret_cast<const bf16x8*>(
            qkv_u + base + (size_t)(nt * 16 + lane15) * 768 + g4 * 8);

    floatx4 S[4][4] = {};
#pragma unroll
    for (int mt = 0; mt < 4; ++mt)
#pragma unroll
        for (int nt = 0; nt < 4; ++nt)
            S[mt][nt] = __builtin_amdgcn_mfma_f32_16x16x32_bf16(
                kf[mt], qf[nt], S[mt][nt], 0, 0, 0);

    const int wr_ = (b_ & 63) >> 3, wc_ = (b_ & 63) & 7;
    int qlin[4], qreg[4];
#pragma unroll
    for (int nt = 0; nt < 4; ++nt) {
        int q = nt * 16 + lane15;
        int qr = (q * 147) >> 10, qc = q - qr * 7;
        qlin[nt] = q + 6 * qr + 84;
        qreg[nt] = ((wr_ == 7) ? ((qr < 4) ? 1 : 2) : 0) * 3
                 + ((wc_ == 7) ? ((qc < 4) ? 1 : 2) : 0);
    }

#pragma unroll
    for (int mt = 0; mt < 4; ++mt)
#pragma unroll
        for (int r = 0; r < 4; ++r) {
            int key = mt * 16 + g4 * 4 + r;
            int kr = (key * 147) >> 10, kc = key - kr * 7;
            int klin = key + 6 * kr;
            int kreg = ((wr_ == 7) ? ((kr < 4) ? 1 : 2) : 0) * 3
                     + ((wc_ == 7) ? ((kc < 4) ? 1 : 2) : 0);
            bool pad = key >= NTOK;
#pragma unroll
            for (int nt = 0; nt < 4; ++nt) {
                int idx = qlin[nt] - klin;
                idx = idx < 0 ? 0 : (idx > 168 ? 168 : idx);
                float s = S[mt][nt][r] + rpbw[idx]
                        + ((qreg[nt] == kreg) ? 0.f : -100.f);
                S[mt][nt][r] = pad ? -1e30f : s;
            }
        }

    float Cfg[4], Cbg[4];
#pragma unroll
    for (int nt = 0; nt < 4; ++nt) {
        float mfg = -3e38f, mbg = -3e38f;
#pragma unroll
        for (int mt = 0; mt < 4; ++mt)
#pragma unroll
            for (int r = 0; r < 4; ++r) {
                int key = mt * 16 + g4 * 4 + r;
                bool fg = (fgmask >> key) & 1ULL;
                float s = S[mt][nt][r];
                mfg = fg ? fmaxf(mfg, s) : mfg;
                mbg = fg ? mbg : fmaxf(mbg, s);
            }
        mfg = fmaxf(mfg, __shfl_xor(mfg, 16)); mfg = fmaxf(mfg, __shfl_xor(mfg, 32));
        mbg = fmaxf(mbg, __shfl_xor(mbg, 16)); mbg = fmaxf(mbg, __shfl_xor(mbg, 32));
        float t1 = 0.f, t2 = 0.f;
#pragma unroll
        for (int mt = 0; mt < 4; ++mt)
#pragma unroll
            for (int r = 0; r < 4; ++r) {
                int key = mt * 16 + g4 * 4 + r;
                bool fg = (fgmask >> key) & 1ULL;
                float e = __expf(S[mt][nt][r] - (fg ? mfg : mbg));
                S[mt][nt][r] = e;
                t1 += fg ? e : 0.f;
                t2 += fg ? 0.f : e;
            }
        t1 += __shfl_xor(t1, 16); t1 += __shfl_xor(t1, 32);
        t2 += __shfl_xor(t2, 16); t2 += __shfl_xor(t2, 32);
        const float m0 = fmaxf(mfg, mbg);
        const float m1 = fmaxf(mfg, mbg - 100.f);
        const float m2 = fmaxf(mfg - 100.f, mbg);
        const float a1 = __expf(mfg - m0),          a2 = __expf(mbg - m0);
        const float b1 = __expf(mfg - m1),          b2 = __expf(mbg - 100.f - m1);
        const float c1 = __expf(mfg - 100.f - m2),  c2 = __expf(mbg - m2);
        const float r0 = 1.f / (t1 * a1 + t2 * a2);
        const float r1 = 1.f / (t1 * b1 + t2 * b2);
        const float r2 = 1.f / (t1 * c1 + t2 * c2);
        Cfg[nt] = a1 * r0 + b1 * r1 - c1 * r2;
        Cbg[nt] = a2 * r0 + b2 * r1 - c2 * r2;
    }

    floatx4 Oc[4][2] = {};
#pragma unroll
    for (int kc = 0; kc < 2; ++kc) {
#pragma unroll
        for (int mh = 0; mh < 2; ++mh) {
            const int mt = kc * 2 + mh;
#pragma unroll
            for (int rp = 0; rp < 2; ++rp) {
                const int key0 = mt * 16 + g4 * 4 + 2 * rp;
                const bool fg0 = (fgmask >> key0) & 1ULL;
                const bool fg1 = (fgmask >> (key0 + 1)) & 1ULL;
                const int keyLocal = key0 - kc * 32;
#pragma unroll
                for (int nt = 0; nt < 4; ++nt) {
                    float pA = S[mt][nt][2 * rp]     * (fg0 ? Cfg[nt] : Cbg[nt]);
                    float pB = S[mt][nt][2 * rp + 1] * (fg1 ? Cfg[nt] : Cbg[nt]);
                    union { __hip_bfloat16 hh[2]; unsigned u; } pk;
                    pk.hh[0] = __float2bfloat16(pA);
                    pk.hh[1] = __float2bfloat16(pB);
                    const int q = nt * 16 + lane15;
                    *reinterpret_cast<unsigned*>(Pw + q * 40 + keyLocal) = pk.u;
                }
            }
        }
        bf16x8 pa[4], vb[2];
#pragma unroll
        for (int mtile = 0; mtile < 4; ++mtile)
            pa[mtile] = *reinterpret_cast<const bf16x8*>(
                Pw + (mtile * 16 + lane15) * 40 + g4 * 8);
#pragma unroll
        for (int n2 = 0; n2 < 2; ++n2)
            vb[n2] = *reinterpret_cast<const bf16x8*>(
                Vw + (n2 * 16 + lane15) * 72 + kc * 32 + g4 * 8);
#pragma unroll
        for (int mtile = 0; mtile < 4; ++mtile)
#pragma unroll
            for (int n2 = 0; n2 < 2; ++n2)
                Oc[mtile][n2] = __builtin_amdgcn_mfma_f32_16x16x32_bf16(
                    pa[mtile], vb[n2], Oc[mtile][n2], 0, 0, 0);
    }

#pragma unroll
    for (int mt = 0; mt < 4; ++mt)
#pragma unroll
        for (int r = 0; r < 4; ++r) {
            int query = mt * 16 + g4 * 4 + r;
            if (query < NTOK) {
                __hip_bfloat16* op = o + ((size_t)b_ * NTOK + query) * CDIM + h * DH;
#pragma unroll
                for (int n2 = 0; n2 < 2; ++n2)
                    op[n2 * 16 + lane15] = __float2bfloat16(Oc[mt][n2][r]);
            }
        }
}

// ---------------------------------------------------------------------------
extern "C" void kernel_launch(void* const* d_in, const int* in_sizes, int n_in,
                              void* d_out, int out_size, void* d_ws, size_t ws_size,
                              hipStream_t stream)
{
    const float* x        = (const float*)d_in[0];
    const float* qkv_w    = (const float*)d_in[1];
    const float* qkv_b    = (const float*)d_in[2];
    const float* rpb_tab  = (const float*)d_in[3];
    const float* proj_w   = (const float*)d_in[4];
    const float* proj_b   = (const float*)d_in[5];
    const float* n1g      = (const float*)d_in[6];
    const float* n1b      = (const float*)d_in[7];
    const float* n2g      = (const float*)d_in[8];
    const float* n2b      = (const float*)d_in[9];
    const float* fc1_w    = (const float*)d_in[10];
    const float* fc1_b    = (const float*)d_in[11];
    const float* fc2_w    = (const float*)d_in[12];
    const float* fc2_b    = (const float*)d_in[13];
    const float* sal_fg   = (const float*)d_in[15];

    char* ws = (char*)d_ws;
    __hip_bfloat16* regA = (__hip_bfloat16*)ws;
    __hip_bfloat16* regB = (__hip_bfloat16*)(ws + 205520896);
    float*          x2   = (float*)(ws + 205520896 + 51380224);
    __hip_bfloat16* wbf  = (__hip_bfloat16*)(ws + 205520896 + 51380224 + 102760448);
    __hip_bfloat16* wqkv  = wbf;
    __hip_bfloat16* wproj = wbf + 196608;
    __hip_bfloat16* wfc1  = wbf + 262144;
    __hip_bfloat16* wfc2  = wbf + 524288;

    convert_weights_kernel<<<3072, 256, 0, stream>>>(qkv_w, proj_w, fc1_w, fc2_w, wbf);

    ln_kernel<true><<<MROWS / 4, 256, 0, stream>>>(x, n1g, n1b, regB);

    gemm_qkv<<<dim3(768 / 256, MROWS / 128), 256, 0, stream>>>(
        regB, wqkv, qkv_b, regA, nullptr, MROWS, 768, 256);

    attn_kernel<<<2048 * 2, 256, 0, stream>>>(regA, rpb_tab, sal_fg, regB);

    gemm_proj<<<dim3(1, MROWS / 128), 256, 0, stream>>>(
        regB, wproj, proj_b, x2, x, MROWS, 256, 256);

    ln_kernel<false><<<MROWS / 4, 256, 0, stream>>>(x2, n2g, n2b, regB);

    gemm_fc1<<<dim3(1024 / 256, MROWS / 128), 256, 0, stream>>>(
        regB, wfc1, fc1_b, regA, nullptr, MROWS, 1024, 256);

    gemm_fc2<<<dim3(1, MROWS / 128), 256, 0, stream>>>(
        regA, wfc2, fc2_b, d_out, x2, MROWS, 256, 1024);
}

// Round 6
// 678.420 us; speedup vs baseline: 1.1663x; 1.0095x over previous
//
#include <hip/hip_runtime.h>
#include <hip/hip_bf16.h>

// Problem constants
#define HH 56
#define WWD 56
#define WIN 7
#define SHIFT 3
#define HEADS 8
#define NTOK 49        // WIN*WIN
#define NW 64          // (56/7)^2
#define CDIM 256
#define DH 32          // CDIM/HEADS
#define MROWS 100352   // B*nW*NTOK = 2048*49
#define SCALE_Q 0.17677669529663687f

typedef float floatx4 __attribute__((ext_vector_type(4)));
typedef __bf16 bf16x8 __attribute__((ext_vector_type(8)));

__device__ __forceinline__ float wave_sum(float v) {
#pragma unroll
    for (int m = 1; m < 64; m <<= 1) v += __shfl_xor(v, m);
    return v;
}

__device__ __forceinline__ void glds16(const void* g, void* l) {
    __builtin_amdgcn_global_load_lds(
        (const __attribute__((address_space(1))) void*)g,
        (__attribute__((address_space(3))) void*)l, 16, 0, 0);
}

// ---------------------------------------------------------------------------
// Weight fp32 -> bf16 conversion
__global__ __launch_bounds__(256) void convert_weights_kernel(
    const float* __restrict__ qkv_w, const float* __restrict__ proj_w,
    const float* __restrict__ fc1_w, const float* __restrict__ fc2_w,
    __hip_bfloat16* __restrict__ dst)
{
    int i = blockIdx.x * 256 + threadIdx.x;
    float v;
    if (i < 196608)       v = qkv_w[i];
    else if (i < 262144)  v = proj_w[i - 196608];
    else if (i < 524288)  v = fc1_w[i - 262144];
    else                  v = fc2_w[i - 524288];
    dst[i] = __float2bfloat16(v);
}

// ---------------------------------------------------------------------------
// LayerNorm; SHIFTED=true also applies roll(-3,-3) + window partition scatter.
template <bool SHIFTED>
__global__ __launch_bounds__(256) void ln_kernel(
    const float* __restrict__ x, const float* __restrict__ g,
    const float* __restrict__ bb, __hip_bfloat16* __restrict__ out)
{
    const int tok  = blockIdx.x * 4 + (threadIdx.x >> 6);
    const int lane = threadIdx.x & 63;
    const int c    = lane * 4;

    float4 v = *reinterpret_cast<const float4*>(x + (size_t)tok * CDIM + c);
    float s = v.x + v.y + v.z + v.w;
    s = wave_sum(s);
    const float mean = s * (1.0f / 256.0f);
    float d0 = v.x - mean, d1 = v.y - mean, d2 = v.z - mean, d3 = v.w - mean;
    float sq = d0 * d0 + d1 * d1 + d2 * d2 + d3 * d3;
    sq = wave_sum(sq);
    const float rstd = rsqrtf(sq * (1.0f / 256.0f) + 1e-5f);

    float4 gv = *reinterpret_cast<const float4*>(g + c);
    float4 bv = *reinterpret_cast<const float4*>(bb + c);

    union { __hip_bfloat16 h[4]; uint2 u; } pk;
    pk.h[0] = __float2bfloat16(d0 * rstd * gv.x + bv.x);
    pk.h[1] = __float2bfloat16(d1 * rstd * gv.y + bv.y);
    pk.h[2] = __float2bfloat16(d2 * rstd * gv.z + bv.z);
    pk.h[3] = __float2bfloat16(d3 * rstd * gv.w + bv.w);

    size_t oidx;
    if (SHIFTED) {
        int b = tok / 3136;
        int l = tok - b * 3136;
        int h = l / WWD, w = l - (l / WWD) * WWD;
        int hp = h - SHIFT; if (hp < 0) hp += HH;
        int wp = w - SHIFT; if (wp < 0) wp += WWD;
        int bwin = b * NW + (hp / WIN) * 8 + (wp / WIN);
        int n = (hp % WIN) * WIN + (wp % WIN);
        oidx = ((size_t)bwin * NTOK + n) * CDIM + c;
    } else {
        oidx = (size_t)tok * CDIM + c;
    }
    *reinterpret_cast<uint2*>(out + oidx) = pk.u;
}

// ---------------------------------------------------------------------------
// Wide bf16 MFMA GEMM: 128x256 tile, BK=32, global_load_lds(16B), XOR-swizzled
// LDS chunks, 3-buffer depth-2 pipeline with counted s_waitcnt vmcnt(6) + raw
// s_barrier. Bijective XCD-chunked blockIdx swizzle. 72 KB LDS.
// NEW: MODE 0/2 (bf16 outputs) use a coalesced LDS-staged epilogue — each wave
// stages its 64x128 bf16 subtile in LDS (stride 136, wave-private), then emits
// ds_read_b128 + global_store_dwordx4 (16 B/lane) instead of 128 x 2B scalar
// stores (which were 4x the L2 request count).
// MODE 0: qkv (scale q cols, bf16). MODE 1: proj (scatter+residual, f32).
// MODE 2: fc1 (GELU tanh-approx, bf16). MODE 3: fc2 (residual, f32).
template <int MODE>
__device__ __forceinline__ void gemm_wide_body(
    const __hip_bfloat16* __restrict__ A,
    const __hip_bfloat16* __restrict__ Wt,
    const float* __restrict__ bias,
    void* __restrict__ outv,
    const float* __restrict__ aux,
    int M, int Nn, int K)
{
    // single block: As = SMEM[0..12287], Bs = SMEM[12288..36863] (73728 B);
    // epilogue reuses the whole region as 4 x (64 x 136) bf16 wave tiles.
    __shared__ __align__(16) __hip_bfloat16 SMEM[3 * 4096 + 3 * 8192];
    __hip_bfloat16* const Asb = SMEM;            // [3][128*32]
    __hip_bfloat16* const Bsb = SMEM + 12288;    // [3][256*32]

    const int tid = threadIdx.x;
    const int wave = tid >> 6, lane = tid & 63;

    // ---- XCD-aware chunked remap (bijective, m204 form)
    const int nwg  = gridDim.x * gridDim.y;
    const int orig = blockIdx.y * gridDim.x + blockIdx.x;
    const int q = nwg >> 3, r = nwg & 7;
    const int xcd = orig & 7, loc = orig >> 3;
    const int lin = (xcd < r ? xcd * (q + 1) : r * (q + 1) + (xcd - r) * q) + loc;
    const int bx = lin % gridDim.x;
    const int by = lin / gridDim.x;

    const int m0 = by * 128, n0 = bx * 256;
    const int fm = lane & 15;
    const int g4 = lane >> 4;
    const int wr = (wave >> 1) * 64;     // 2 row-groups of 64
    const int wc = (wave & 1) * 128;     // 2 col-groups of 128

    floatx4 acc[4][8] = {};

    // staging lane constants: A uses chunks j=0,1 (128 rows); B uses j=0..3
    const int c0 = wave * 64 + lane;
    int rj[4], gj[4];
#pragma unroll
    for (int j = 0; j < 4; ++j) {
        const int cj = j * 256 + c0;
        rj[j] = cj >> 2;
        const int pj = cj & 3;
        gj[j] = pj ^ ((rj[j] >> 1) & 3);
    }
    const __hip_bfloat16* gA0 = A + (size_t)(m0 + rj[0]) * K + gj[0] * 8;
    const __hip_bfloat16* gA1 = A + (size_t)(m0 + rj[1]) * K + gj[1] * 8;
    const __hip_bfloat16* gB0 = Wt + (size_t)(n0 + rj[0]) * K + gj[0] * 8;
    const __hip_bfloat16* gB1 = Wt + (size_t)(n0 + rj[1]) * K + gj[1] * 8;
    const __hip_bfloat16* gB2 = Wt + (size_t)(n0 + rj[2]) * K + gj[2] * 8;
    const __hip_bfloat16* gB3 = Wt + (size_t)(n0 + rj[3]) * K + gj[3] * 8;
    const int ab0 = wave * 512, ab1 = 2048 + wave * 512;
    const int bb0 = wave * 512, bb1 = 2048 + wave * 512;
    const int bb2 = 4096 + wave * 512, bb3 = 6144 + wave * 512;

    const int nt = K >> 5;

    // ---- prologue: stage tiles 0,1
#pragma unroll
    for (int pp = 0; pp < 2; ++pp) {
        const int kp = pp << 5;
        glds16(gA0 + kp, Asb + pp * 4096 + ab0);
        glds16(gA1 + kp, Asb + pp * 4096 + ab1);
        glds16(gB0 + kp, Bsb + pp * 8192 + bb0);
        glds16(gB1 + kp, Bsb + pp * 8192 + bb1);
        glds16(gB2 + kp, Bsb + pp * 8192 + bb2);
        glds16(gB3 + kp, Bsb + pp * 8192 + bb3);
    }
    asm volatile("s_waitcnt vmcnt(6)" ::: "memory");   // tile 0 resident
    __builtin_amdgcn_s_barrier();
    __builtin_amdgcn_sched_barrier(0);

    int cur = 0;
    for (int tt = 0; tt < nt; ++tt) {
        if (tt + 2 < nt) {
            const int nx2 = (cur >= 1) ? cur - 1 : cur + 2;
            const int k2 = (tt + 2) << 5;
            glds16(gA0 + k2, Asb + nx2 * 4096 + ab0);
            glds16(gA1 + k2, Asb + nx2 * 4096 + ab1);
            glds16(gB0 + k2, Bsb + nx2 * 8192 + bb0);
            glds16(gB1 + k2, Bsb + nx2 * 8192 + bb1);
            glds16(gB2 + k2, Bsb + nx2 * 8192 + bb2);
            glds16(gB3 + k2, Bsb + nx2 * 8192 + bb3);
        }

        const __hip_bfloat16* Ac = Asb + cur * 4096;
        const __hip_bfloat16* Bc = Bsb + cur * 8192;
        bf16x8 af[4], bfr[8];
#pragma unroll
        for (int mt = 0; mt < 4; ++mt) {
            const int ml = wr + mt * 16 + fm;
            af[mt] = *reinterpret_cast<const bf16x8*>(
                Ac + ml * 32 + ((g4 ^ ((ml >> 1) & 3)) * 8));
        }
#pragma unroll
        for (int nn = 0; nn < 8; ++nn) {
            const int nl = wc + nn * 16 + fm;
            bfr[nn] = *reinterpret_cast<const bf16x8*>(
                Bc + nl * 32 + ((g4 ^ ((nl >> 1) & 3)) * 8));
        }
#pragma unroll
        for (int mt = 0; mt < 4; ++mt)
#pragma unroll
            for (int nn = 0; nn < 8; ++nn)
                acc[mt][nn] = __builtin_amdgcn_mfma_f32_16x16x32_bf16(
                    af[mt], bfr[nn], acc[mt][nn], 0, 0, 0);

        if (tt + 1 < nt) {
            if (tt + 2 < nt)
                asm volatile("s_waitcnt vmcnt(6) lgkmcnt(0)" ::: "memory");
            else
                asm volatile("s_waitcnt vmcnt(0) lgkmcnt(0)" ::: "memory");
            __builtin_amdgcn_s_barrier();
            __builtin_amdgcn_sched_barrier(0);
        }
        cur = (cur >= 2) ? 0 : cur + 1;
    }

    float bv[8];
#pragma unroll
    for (int nn = 0; nn < 8; ++nn) bv[nn] = bias[n0 + wc + nn * 16 + fm];

    if (MODE == 0 || MODE == 2) {
        // ---- coalesced LDS-staged bf16 epilogue -----------------------------
        __syncthreads();   // all waves done reading staging LDS
        __hip_bfloat16* Ep = SMEM + wave * 8704;   // 64 rows x stride 136

#pragma unroll
        for (int mt = 0; mt < 4; ++mt) {
#pragma unroll
            for (int rr = 0; rr < 4; ++rr) {
                const int lrow = mt * 16 + g4 * 4 + rr;
#pragma unroll
                for (int nn = 0; nn < 8; ++nn) {
                    const int n_g = n0 + wc + nn * 16 + fm;
                    float val = acc[mt][nn][rr] + bv[nn];
                    if (MODE == 0) {
                        if (n_g < 256) val *= SCALE_Q;
                    } else {
                        // GELU tanh-approx (robust 1 - 2/(e+1) form)
                        float u  = val;
                        float y2 = 1.5957691216057308f * u
                                 * (1.0f + 0.044715f * u * u);
                        float e  = __expf(y2);
                        float th = 1.0f - 2.0f / (e + 1.0f);
                        val = 0.5f * u * (1.0f + th);
                    }
                    Ep[lrow * 136 + nn * 16 + fm] = __float2bfloat16(val);
                }
            }
        }
        asm volatile("s_waitcnt lgkmcnt(0)" ::: "memory");  // wave-local flush

        __hip_bfloat16* const outp = reinterpret_cast<__hip_bfloat16*>(outv);
#pragma unroll
        for (int i = 0; i < 16; ++i) {
            const int lrow = i * 4 + g4;
            bf16x8 v = *reinterpret_cast<const bf16x8*>(Ep + lrow * 136 + fm * 8);
            *reinterpret_cast<bf16x8*>(
                outp + (size_t)(m0 + wr + lrow) * Nn + n0 + wc + fm * 8) = v;
        }
    } else {
        // ---- f32 epilogues (proj scatter / fc2 residual) --------------------
#pragma unroll
        for (int mt = 0; mt < 4; ++mt) {
#pragma unroll
            for (int rr = 0; rr < 4; ++rr) {
                const int m_g = m0 + wr + mt * 16 + g4 * 4 + rr;
                size_t row_idx = 0;
                if (MODE == 1) {
                    int bwin = m_g / NTOK;
                    int ntok = m_g - bwin * NTOK;
                    int b = bwin >> 6, wi = bwin & 63;
                    int r2 = ntok / WIN, cc = ntok - r2 * WIN;
                    int hp = (wi >> 3) * WIN + r2;
                    int wp = (wi & 7) * WIN + cc;
                    int h = hp + SHIFT; if (h >= HH) h -= HH;
                    int w = wp + SHIFT; if (w >= WWD) w -= WWD;
                    row_idx = ((size_t)b * 3136 + h * WWD + w) * CDIM;
                }
#pragma unroll
                for (int nn = 0; nn < 8; ++nn) {
                    const int n_g = n0 + wc + nn * 16 + fm;
                    float val = acc[mt][nn][rr] + bv[nn];
                    if (MODE == 3) {
                        size_t idx = (size_t)m_g * CDIM + n_g;
                        reinterpret_cast<float*>(outv)[idx] = aux[idx] + val;
                    } else {   // MODE 1
                        size_t idx = row_idx + n_g;
                        reinterpret_cast<float*>(outv)[idx] = aux[idx] + val;
                    }
                }
            }
        }
    }
}

// Distinct symbols per stage for per-dispatch profiling visibility.
__global__ __launch_bounds__(256, 2) void gemm_qkv(
    const __hip_bfloat16* __restrict__ A, const __hip_bfloat16* __restrict__ Wt,
    const float* __restrict__ bias, void* __restrict__ outv,
    const float* __restrict__ aux, int M, int Nn, int K)
{ gemm_wide_body<0>(A, Wt, bias, outv, aux, M, Nn, K); }

__global__ __launch_bounds__(256, 2) void gemm_proj(
    const __hip_bfloat16* __restrict__ A, const __hip_bfloat16* __restrict__ Wt,
    const float* __restrict__ bias, void* __restrict__ outv,
    const float* __restrict__ aux, int M, int Nn, int K)
{ gemm_wide_body<1>(A, Wt, bias, outv, aux, M, Nn, K); }

__global__ __launch_bounds__(256, 2) void gemm_fc1(
    const __hip_bfloat16* __restrict__ A, const __hip_bfloat16* __restrict__ Wt,
    const float* __restrict__ bias, void* __restrict__ outv,
    const float* __restrict__ aux, int M, int Nn, int K)
{ gemm_wide_body<2>(A, Wt, bias, outv, aux, M, Nn, K); }

__global__ __launch_bounds__(256, 2) void gemm_fc2(
    const __hip_bfloat16* __restrict__ A, const __hip_bfloat16* __restrict__ Wt,
    const float* __restrict__ bias, void* __restrict__ outv,
    const float* __restrict__ aux, int M, int Nn, int K)
{ gemm_wide_body<3>(A, Wt, bias, outv, aux, M, Nn, K); }

// ---------------------------------------------------------------------------
// Attention v5 (MFMA + cheap 3-softmax): one wave per (window, head).
__global__ __launch_bounds__(256) void attn_kernel(
    const __hip_bfloat16* __restrict__ qkv,   // (B_,49,768) bf16, q pre-scaled
    const float* __restrict__ rpb_table,      // (169,8)
    const float* __restrict__ sal_fg,         // (B_,49,49): row 0 = key mask
    __hip_bfloat16* __restrict__ o)           // (B_,49,256)
{
    __shared__ unsigned short Pl[4][64 * 40];   // [query][keyHalf] bf16
    __shared__ unsigned short Vt[4][32 * 72];   // [d][key] bf16, stride 72
    __shared__ float rpb_l[4][176];

    const int t = threadIdx.x;
    const int wave = t >> 6, lane = t & 63;
    const int lane15 = lane & 15, g4 = lane >> 4;
    const int b_ = blockIdx.x >> 1;
    const int h = ((blockIdx.x & 1) << 2) | wave;

    unsigned short* Pw = Pl[wave];
    unsigned short* Vw = Vt[wave];
    float* rpbw = rpb_l[wave];

    const unsigned short* qkv_u = reinterpret_cast<const unsigned short*>(qkv);
    const size_t base = (size_t)b_ * (NTOK * 768) + h * DH;

#pragma unroll
    for (int it = 0; it < 32; ++it) {
        int idx = it * 64 + lane;
        int key = idx >> 5, d = idx & 31;
        unsigned short v = (key < NTOK) ? qkv_u[base + key * 768 + 512 + d]
                                        : (unsigned short)0;
        Vw[d * 72 + key] = v;
    }
#pragma unroll
    for (int it = 0; it < 3; ++it) {
        int i = it * 64 + lane;
        if (i < 169) rpbw[i] = rpb_table[i * 8 + h];
    }
    float sfv = (lane < NTOK) ? sal_fg[(size_t)b_ * (NTOK * NTOK) + lane] : -100.f;
    const unsigned long long fgmask = __ballot(sfv == 0.0f);

    bf16x8 kf[4], qf[4];
#pragma unroll
    for (int mt = 0; mt < 4; ++mt)
        kf[mt] = *reinterpret_cast<const bf16x8*>(
            qkv_u + base + (size_t)(mt * 16 + lane15) * 768 + 256 + g4 * 8);
#pragma unroll
    for (int nt = 0; nt < 4; ++nt)
        qf[nt] = *reinterpret_cast<const bf16x8*>(
            qkv_u + base + (size_t)(nt * 16 + lane15) * 768 + g4 * 8);

    floatx4 S[4][4] = {};
#pragma unroll
    for (int mt = 0; mt < 4; ++mt)
#pragma unroll
        for (int nt = 0; nt < 4; ++nt)
            S[mt][nt] = __builtin_amdgcn_mfma_f32_16x16x32_bf16(
                kf[mt], qf[nt], S[mt][nt], 0, 0, 0);

    const int wr_ = (b_ & 63) >> 3, wc_ = (b_ & 63) & 7;
    int qlin[4], qreg[4];
#pragma unroll
    for (int nt = 0; nt < 4; ++nt) {
        int q = nt * 16 + lane15;
        int qr = (q * 147) >> 10, qc = q - qr * 7;
        qlin[nt] = q + 6 * qr + 84;
        qreg[nt] = ((wr_ == 7) ? ((qr < 4) ? 1 : 2) : 0) * 3
                 + ((wc_ == 7) ? ((qc < 4) ? 1 : 2) : 0);
    }

#pragma unroll
    for (int mt = 0; mt < 4; ++mt)
#pragma unroll
        for (int r = 0; r < 4; ++r) {
            int key = mt * 16 + g4 * 4 + r;
            int kr = (key * 147) >> 10, kc = key - kr * 7;
            int klin = key + 6 * kr;
            int kreg = ((wr_ == 7) ? ((kr < 4) ? 1 : 2) : 0) * 3
                     + ((wc_ == 7) ? ((kc < 4) ? 1 : 2) : 0);
            bool pad = key >= NTOK;
#pragma unroll
            for (int nt = 0; nt < 4; ++nt) {
                int idx = qlin[nt] - klin;
                idx = idx < 0 ? 0 : (idx > 168 ? 168 : idx);
                float s = S[mt][nt][r] + rpbw[idx]
                        + ((qreg[nt] == kreg) ? 0.f : -100.f);
                S[mt][nt][r] = pad ? -1e30f : s;
            }
        }

    float Cfg[4], Cbg[4];
#pragma unroll
    for (int nt = 0; nt < 4; ++nt) {
        float mfg = -3e38f, mbg = -3e38f;
#pragma unroll
        for (int mt = 0; mt < 4; ++mt)
#pragma unroll
            for (int r = 0; r < 4; ++r) {
                int key = mt * 16 + g4 * 4 + r;
                bool fg = (fgmask >> key) & 1ULL;
                float s = S[mt][nt][r];
                mfg = fg ? fmaxf(mfg, s) : mfg;
                mbg = fg ? mbg : fmaxf(mbg, s);
            }
        mfg = fmaxf(mfg, __shfl_xor(mfg, 16)); mfg = fmaxf(mfg, __shfl_xor(mfg, 32));
        mbg = fmaxf(mbg, __shfl_xor(mbg, 16)); mbg = fmaxf(mbg, __shfl_xor(mbg, 32));
        float t1 = 0.f, t2 = 0.f;
#pragma unroll
        for (int mt = 0; mt < 4; ++mt)
#pragma unroll
            for (int r = 0; r < 4; ++r) {
                int key = mt * 16 + g4 * 4 + r;
                bool fg = (fgmask >> key) & 1ULL;
                float e = __expf(S[mt][nt][r] - (fg ? mfg : mbg));
                S[mt][nt][r] = e;
                t1 += fg ? e : 0.f;
                t2 += fg ? 0.f : e;
            }
        t1 += __shfl_xor(t1, 16); t1 += __shfl_xor(t1, 32);
        t2 += __shfl_xor(t2, 16); t2 += __shfl_xor(t2, 32);
        const float m0 = fmaxf(mfg, mbg);
        const float m1 = fmaxf(mfg, mbg - 100.f);
        const float m2 = fmaxf(mfg - 100.f, mbg);
        const float a1 = __expf(mfg - m0),          a2 = __expf(mbg - m0);
        const float b1 = __expf(mfg - m1),          b2 = __expf(mbg - 100.f - m1);
        const float c1 = __expf(mfg - 100.f - m2),  c2 = __expf(mbg - m2);
        const float r0 = 1.f / (t1 * a1 + t2 * a2);
        const float r1 = 1.f / (t1 * b1 + t2 * b2);
        const float r2 = 1.f / (t1 * c1 + t2 * c2);
        Cfg[nt] = a1 * r0 + b1 * r1 - c1 * r2;
        Cbg[nt] = a2 * r0 + b2 * r1 - c2 * r2;
    }

    floatx4 Oc[4][2] = {};
#pragma unroll
    for (int kc = 0; kc < 2; ++kc) {
#pragma unroll
        for (int mh = 0; mh < 2; ++mh) {
            const int mt = kc * 2 + mh;
#pragma unroll
            for (int rp = 0; rp < 2; ++rp) {
                const int key0 = mt * 16 + g4 * 4 + 2 * rp;
                const bool fg0 = (fgmask >> key0) & 1ULL;
                const bool fg1 = (fgmask >> (key0 + 1)) & 1ULL;
                const int keyLocal = key0 - kc * 32;
#pragma unroll
                for (int nt = 0; nt < 4; ++nt) {
                    float pA = S[mt][nt][2 * rp]     * (fg0 ? Cfg[nt] : Cbg[nt]);
                    float pB = S[mt][nt][2 * rp + 1] * (fg1 ? Cfg[nt] : Cbg[nt]);
                    union { __hip_bfloat16 hh[2]; unsigned u; } pk;
                    pk.hh[0] = __float2bfloat16(pA);
                    pk.hh[1] = __float2bfloat16(pB);
                    const int q = nt * 16 + lane15;
                    *reinterpret_cast<unsigned*>(Pw + q * 40 + keyLocal) = pk.u;
                }
            }
        }
        bf16x8 pa[4], vb[2];
#pragma unroll
        for (int mtile = 0; mtile < 4; ++mtile)
            pa[mtile] = *reinterpret_cast<const bf16x8*>(
                Pw + (mtile * 16 + lane15) * 40 + g4 * 8);
#pragma unroll
        for (int n2 = 0; n2 < 2; ++n2)
            vb[n2] = *reinterpret_cast<const bf16x8*>(
                Vw + (n2 * 16 + lane15) * 72 + kc * 32 + g4 * 8);
#pragma unroll
        for (int mtile = 0; mtile < 4; ++mtile)
#pragma unroll
            for (int n2 = 0; n2 < 2; ++n2)
                Oc[mtile][n2] = __builtin_amdgcn_mfma_f32_16x16x32_bf16(
                    pa[mtile], vb[n2], Oc[mtile][n2], 0, 0, 0);
    }

#pragma unroll
    for (int mt = 0; mt < 4; ++mt)
#pragma unroll
        for (int r = 0; r < 4; ++r) {
            int query = mt * 16 + g4 * 4 + r;
            if (query < NTOK) {
                __hip_bfloat16* op = o + ((size_t)b_ * NTOK + query) * CDIM + h * DH;
#pragma unroll
                for (int n2 = 0; n2 < 2; ++n2)
                    op[n2 * 16 + lane15] = __float2bfloat16(Oc[mt][n2][r]);
            }
        }
}

// ---------------------------------------------------------------------------
extern "C" void kernel_launch(void* const* d_in, const int* in_sizes, int n_in,
                              void* d_out, int out_size, void* d_ws, size_t ws_size,
                              hipStream_t stream)
{
    const float* x        = (const float*)d_in[0];
    const float* qkv_w    = (const float*)d_in[1];
    const float* qkv_b    = (const float*)d_in[2];
    const float* rpb_tab  = (const float*)d_in[3];
    const float* proj_w   = (const float*)d_in[4];
    const float* proj_b   = (const float*)d_in[5];
    const float* n1g      = (const float*)d_in[6];
    const float* n1b      = (const float*)d_in[7];
    const float* n2g      = (const float*)d_in[8];
    const float* n2b      = (const float*)d_in[9];
    const float* fc1_w    = (const float*)d_in[10];
    const float* fc1_b    = (const float*)d_in[11];
    const float* fc2_w    = (const float*)d_in[12];
    const float* fc2_b    = (const float*)d_in[13];
    const float* sal_fg   = (const float*)d_in[15];

    char* ws = (char*)d_ws;
    __hip_bfloat16* regA = (__hip_bfloat16*)ws;
    __hip_bfloat16* regB = (__hip_bfloat16*)(ws + 205520896);
    float*          x2   = (float*)(ws + 205520896 + 51380224);
    __hip_bfloat16* wbf  = (__hip_bfloat16*)(ws + 205520896 + 51380224 + 102760448);
    __hip_bfloat16* wqkv  = wbf;
    __hip_bfloat16* wproj = wbf + 196608;
    __hip_bfloat16* wfc1  = wbf + 262144;
    __hip_bfloat16* wfc2  = wbf + 524288;

    convert_weights_kernel<<<3072, 256, 0, stream>>>(qkv_w, proj_w, fc1_w, fc2_w, wbf);

    ln_kernel<true><<<MROWS / 4, 256, 0, stream>>>(x, n1g, n1b, regB);

    gemm_qkv<<<dim3(768 / 256, MROWS / 128), 256, 0, stream>>>(
        regB, wqkv, qkv_b, regA, nullptr, MROWS, 768, 256);

    attn_kernel<<<2048 * 2, 256, 0, stream>>>(regA, rpb_tab, sal_fg, regB);

    gemm_proj<<<dim3(1, MROWS / 128), 256, 0, stream>>>(
        regB, wproj, proj_b, x2, x, MROWS, 256, 256);

    ln_kernel<false><<<MROWS / 4, 256, 0, stream>>>(x2, n2g, n2b, regB);

    gemm_fc1<<<dim3(1024 / 256, MROWS / 128), 256, 0, stream>>>(
        regB, wfc1, fc1_b, regA, nullptr, MROWS, 1024, 256);

    gemm_fc2<<<dim3(1, MROWS / 128), 256, 0, stream>>>(
        regA, wfc2, fc2_b, d_out, x2, MROWS, 256, 1024);
}